// Round 2
// baseline (459.311 us; speedup 1.0000x reference)
//
#include <hip/hip_runtime.h>
#include <math.h>

#define EPS 1e-5f

// Shapes: B=64, C=96, H=W=56, HW=3136, planes = 6144

// ---------------- K1: global average pool + (last block) kernel predictor ---
// ws layout: [0..3] counter (zeroed via hipMemsetAsync), float offset 64:
// pooled[6144], then sel[64] ints.
__global__ __launch_bounds__(256) void pool_sel_kernel(
    const float* __restrict__ x,
    float* __restrict__ pooled, unsigned* __restrict__ counter,
    const float* __restrict__ kw1, const float* __restrict__ kg1,
    const float* __restrict__ kb1, const float* __restrict__ km1,
    const float* __restrict__ kv1,
    const float* __restrict__ kw2, const float* __restrict__ kg2,
    const float* __restrict__ kb2, const float* __restrict__ km2,
    const float* __restrict__ kv2,
    int* __restrict__ sel) {
    __shared__ float smem[6208];   // 64 samples x stride 97 (bank-conflict-free)
    __shared__ float wsum[4];
    __shared__ int lastflag;
    const int bc = blockIdx.x;
    const int tid = threadIdx.x;

    const float4* xp4 = (const float4*)(x + (size_t)bc * 3136);
    float s = 0.f;
    for (int i = tid; i < 784; i += 256) {
        float4 v = xp4[i];
        s += (v.x + v.y) + (v.z + v.w);
    }
    for (int off = 32; off > 0; off >>= 1) s += __shfl_down(s, off, 64);
    if ((tid & 63) == 0) wsum[tid >> 6] = s;
    __syncthreads();
    if (tid == 0) {
        float t = (wsum[0] + wsum[1]) + (wsum[2] + wsum[3]);
        __hip_atomic_store(&pooled[bc], t * (1.f / 3136.f),
                           __ATOMIC_RELEASE, __HIP_MEMORY_SCOPE_AGENT);
        __threadfence();
        unsigned old = __hip_atomic_fetch_add(counter, 1u, __ATOMIC_ACQ_REL,
                                              __HIP_MEMORY_SCOPE_AGENT);
        lastflag = (old == (unsigned)(gridDim.x - 1));
    }
    __syncthreads();
    if (!lastflag) return;

    // last-to-finish block: all pooled values are globally visible now
    __threadfence();
    for (int i = tid; i < 6144; i += 256) {
        float v = __hip_atomic_load(&pooled[i], __ATOMIC_RELAXED,
                                    __HIP_MEMORY_SCOPE_AGENT);
        int bb = i / 96;
        smem[bb * 97 + (i - bb * 96)] = v;
    }
    __syncthreads();
    if (tid < 64) {
        const float* p = &smem[tid * 97];
        double h1[4];
#pragma unroll
        for (int j = 0; j < 4; ++j) {
            double acc = 0.0;
            for (int c = 0; c < 96; ++c)
                acc += (double)p[c] * (double)kw1[j * 96 + c];
            double sg = (double)kg1[j] / sqrt((double)kv1[j] + 1e-5);
            double h = acc * sg + ((double)kb1[j] - (double)km1[j] * sg);
            h1[j] = h * 0.5 * (1.0 + erf(h * 0.70710678118654752440));
        }
        double h2[2];
#pragma unroll
        for (int k = 0; k < 2; ++k) {
            double acc = 0.0;
#pragma unroll
            for (int j = 0; j < 4; ++j) acc += h1[j] * (double)kw2[k * 4 + j];
            double sg = (double)kg2[k] / sqrt((double)kv2[k] + 1e-5);
            h2[k] = acc * sg + ((double)kb2[k] - (double)km2[k] * sg);
        }
        sel[tid] = (h2[0] > h2[1]) ? 1 : 0;
    }
}

// ---------------- K2: fused depthwise conv + BNs, rolling register window ---
// thread = (bc, ysplit 0..3, qstrip 0..13); 14 rows x 4 cols per thread.
// Unified 5x5 tap array (3x3 branch embedded, outer ring zero) -> no tap-loop
// divergence; 1x1 conv folded into center tap; all BNs folded into wg/Cc.
__global__ __launch_bounds__(256) void conv_kernel(
    const float* __restrict__ x,
    const float* __restrict__ w3, const float* __restrict__ g3,
    const float* __restrict__ b3, const float* __restrict__ m3,
    const float* __restrict__ v3,
    const float* __restrict__ w5, const float* __restrict__ g5,
    const float* __restrict__ b5, const float* __restrict__ m5,
    const float* __restrict__ v5,
    const float* __restrict__ w1, const float* __restrict__ b1,
    const float* __restrict__ gbn, const float* __restrict__ bbn,
    const float* __restrict__ mbn, const float* __restrict__ vbn,
    const int* __restrict__ sel, float* __restrict__ out) {
    const int t = blockIdx.x * 256 + threadIdx.x;   // 344064 total
    const int q = t % 14;
    const int r = t / 14;
    const int ys = r & 3;
    const int bc = r >> 2;
    const int b = bc / 96;
    const int c = bc - b * 96;
    const int y0 = ys * 14;
    const float* __restrict__ base = x + (size_t)bc * 3136;

    const float sbn = gbn[c] * rsqrtf(vbn[c] + EPS);
    const float tbn = bbn[c] - mbn[c] * sbn;
    float wg[25];
    float Cc;
    if (sel[b]) {
        const float sk = g3[c] * rsqrtf(v3[c] + EPS);
        const float A = sbn * sk;
#pragma unroll
        for (int i = 0; i < 25; ++i) wg[i] = 0.f;
#pragma unroll
        for (int ky = 0; ky < 3; ++ky)
#pragma unroll
            for (int kx = 0; kx < 3; ++kx)
                wg[(ky + 1) * 5 + (kx + 1)] = A * w3[c * 9 + ky * 3 + kx];
        Cc = sbn * ((b3[c] - m3[c] * sk) + b1[c]) + tbn;
    } else {
        const float sk = g5[c] * rsqrtf(v5[c] + EPS);
        const float A = sbn * sk;
#pragma unroll
        for (int i = 0; i < 25; ++i) wg[i] = A * w5[c * 25 + i];
        Cc = sbn * ((b5[c] - m5[c] * sk) + b1[c]) + tbn;
    }
    wg[12] += sbn * w1[c];

    // rolling 5-row x 8-col window: col index i holds image col 4q-2+i
    float f[5][8];
    auto load_row = [&](int row, float* dst) {
        if ((unsigned)row > 55u) {
#pragma unroll
            for (int i = 0; i < 8; ++i) dst[i] = 0.f;
            return;
        }
        const float* rp = base + row * 56;
        float2 Aa = *(const float2*)(rp + (q > 0 ? 4 * q - 2 : 0));   // 8B aligned
        float4 Bv = *(const float4*)(rp + 4 * q);                     // 16B aligned
        float2 Cv = *(const float2*)(rp + (q < 13 ? 4 * q + 4 : 48)); // 16B aligned
        if (q == 0) { Aa.x = 0.f; Aa.y = 0.f; }
        if (q == 13) { Cv.x = 0.f; Cv.y = 0.f; }
        dst[0] = Aa.x; dst[1] = Aa.y;
        dst[2] = Bv.x; dst[3] = Bv.y; dst[4] = Bv.z; dst[5] = Bv.w;
        dst[6] = Cv.x; dst[7] = Cv.y;
    };

#pragma unroll
    for (int i = 0; i < 4; ++i) load_row(y0 - 2 + i, f[i]);

    float* op = out + (size_t)bc * 3136 + y0 * 56 + 4 * q;
#pragma unroll
    for (int j = 0; j < 14; ++j) {
        load_row(y0 + 2 + j, f[(4 + j) % 5]);
        float a0 = Cc, a1 = Cc, a2 = Cc, a3 = Cc;
#pragma unroll
        for (int ky = 0; ky < 5; ++ky) {
            const float* fr = f[(j + ky) % 5];
#pragma unroll
            for (int kx = 0; kx < 5; ++kx) {
                const float w = wg[ky * 5 + kx];
                a0 = fmaf(w, fr[kx], a0);
                a1 = fmaf(w, fr[kx + 1], a1);
                a2 = fmaf(w, fr[kx + 2], a2);
                a3 = fmaf(w, fr[kx + 3], a3);
            }
        }
        *(float4*)op = make_float4(a0, a1, a2, a3);
        op += 56;
    }
}

extern "C" void kernel_launch(void* const* d_in, const int* in_sizes, int n_in,
                              void* d_out, int out_size, void* d_ws, size_t ws_size,
                              hipStream_t stream) {
    const float* x   = (const float*)d_in[0];
    const float* w3  = (const float*)d_in[1];
    const float* g3  = (const float*)d_in[2];
    const float* b3  = (const float*)d_in[3];
    const float* m3  = (const float*)d_in[4];
    const float* v3  = (const float*)d_in[5];
    const float* w5  = (const float*)d_in[6];
    const float* g5  = (const float*)d_in[7];
    const float* b5  = (const float*)d_in[8];
    const float* m5  = (const float*)d_in[9];
    const float* v5  = (const float*)d_in[10];
    const float* w1  = (const float*)d_in[11];
    const float* b1  = (const float*)d_in[12];
    const float* gbn = (const float*)d_in[13];
    const float* bbn = (const float*)d_in[14];
    const float* mbn = (const float*)d_in[15];
    const float* vbn = (const float*)d_in[16];
    const float* kw1 = (const float*)d_in[17];
    const float* kg1 = (const float*)d_in[18];
    const float* kb1 = (const float*)d_in[19];
    const float* km1 = (const float*)d_in[20];
    const float* kv1 = (const float*)d_in[21];
    const float* kw2 = (const float*)d_in[22];
    const float* kg2 = (const float*)d_in[23];
    const float* kb2 = (const float*)d_in[24];
    const float* km2 = (const float*)d_in[25];
    const float* kv2 = (const float*)d_in[26];
    float* out = (float*)d_out;

    unsigned* counter = (unsigned*)d_ws;
    float* pooled = (float*)d_ws + 64;          // 6144 floats
    int* sel = (int*)((float*)d_ws + 64 + 6144);

    hipMemsetAsync(counter, 0, 4, stream);      // graph-capturable
    pool_sel_kernel<<<6144, 256, 0, stream>>>(
        x, pooled, counter, kw1, kg1, kb1, km1, kv1,
        kw2, kg2, kb2, km2, kv2, sel);
    conv_kernel<<<1344, 256, 0, stream>>>(
        x, w3, g3, b3, m3, v3, w5, g5, b5, m5, v5, w1, b1,
        gbn, bbn, mbn, vbn, sel, out);
}

// Round 3
// 219.703 us; speedup vs baseline: 2.0906x; 2.0906x over previous
//
#include <hip/hip_runtime.h>
#include <math.h>

#define EPS 1e-5f

// Shapes: B=64, C=96, H=W=56, HW=3136, planes = 6144
// Thread map (conv): t = (bc, ysplit 0..3, qstrip 0..13); 5376 threads per
// sample = 84 waves exactly -> every wave/block is sample-uniform, so the
// sel[b] branch never diverges.

// ---------------- K1: global average pool: x (B,C,56,56) -> pooled (B*C) ----
__global__ __launch_bounds__(256) void pool_kernel(const float* __restrict__ x,
                                                   float* __restrict__ pooled) {
    const int bc = blockIdx.x;
    const float4* xp4 = (const float4*)(x + (size_t)bc * 3136);
    const int tid = threadIdx.x;
    float s = 0.f;
    for (int i = tid; i < 784; i += 256) {
        float4 v = xp4[i];
        s += (v.x + v.y) + (v.z + v.w);
    }
    for (int off = 32; off > 0; off >>= 1) s += __shfl_down(s, off, 64);
    __shared__ float wsum[4];
    if ((tid & 63) == 0) wsum[tid >> 6] = s;
    __syncthreads();
    if (tid == 0) {
        float t = (wsum[0] + wsum[1]) + (wsum[2] + wsum[3]);
        pooled[bc] = t * (1.f / 3136.f);
    }
}

// ---------------- K2: kernel predictor MLP -> sel[b] in {0,1} ---------------
// sel=1 means take the 3x3 branch (kwts[:,0] > kwts[:,1]; softmax monotone)
__global__ __launch_bounds__(64) void sel_kernel(
    const float* __restrict__ pooled,
    const float* __restrict__ kw1, const float* __restrict__ kg1,
    const float* __restrict__ kb1, const float* __restrict__ km1,
    const float* __restrict__ kv1,
    const float* __restrict__ kw2, const float* __restrict__ kg2,
    const float* __restrict__ kb2, const float* __restrict__ km2,
    const float* __restrict__ kv2,
    int* __restrict__ sel) {
    const int b = threadIdx.x;  // 64 threads, one per sample
    const float* p = pooled + b * 96;
    double h1[4];
#pragma unroll
    for (int j = 0; j < 4; ++j) {
        double acc = 0.0;
        for (int c = 0; c < 96; ++c)
            acc += (double)p[c] * (double)kw1[j * 96 + c];
        double s = (double)kg1[j] / sqrt((double)kv1[j] + 1e-5);
        double h = acc * s + ((double)kb1[j] - (double)km1[j] * s);
        h1[j] = h * 0.5 * (1.0 + erf(h * 0.70710678118654752440));  // exact gelu
    }
    double h2[2];
#pragma unroll
    for (int k = 0; k < 2; ++k) {
        double acc = 0.0;
#pragma unroll
        for (int j = 0; j < 4; ++j) acc += h1[j] * (double)kw2[k * 4 + j];
        double s = (double)kg2[k] / sqrt((double)kv2[k] + 1e-5);
        h2[k] = acc * s + ((double)kb2[k] - (double)km2[k] * s);
    }
    sel[b] = (h2[0] > h2[1]) ? 1 : 0;
}

// ---------------- K3: fused depthwise conv + BNs, rolling register window ---
__device__ __forceinline__ float2 pk_fma(float2 a, float2 b, float2 c) {
    return make_float2(fmaf(a.x, b.x, c.x), fmaf(a.y, b.y, c.y));
}

__global__ __launch_bounds__(256) void conv_kernel(
    const float* __restrict__ x,
    const float* __restrict__ w3, const float* __restrict__ g3,
    const float* __restrict__ b3, const float* __restrict__ m3,
    const float* __restrict__ v3,
    const float* __restrict__ w5, const float* __restrict__ g5,
    const float* __restrict__ b5, const float* __restrict__ m5,
    const float* __restrict__ v5,
    const float* __restrict__ w1, const float* __restrict__ b1,
    const float* __restrict__ gbn, const float* __restrict__ bbn,
    const float* __restrict__ mbn, const float* __restrict__ vbn,
    const int* __restrict__ sel, float* __restrict__ out) {
    const int t = blockIdx.x * 256 + threadIdx.x;   // 344064 total
    const int q = t % 14;
    const int r = t / 14;
    const int ys = r & 3;
    const int bc = r >> 2;
    const int b = bc / 96;
    const int c = bc - b * 96;
    const int y0 = ys * 14;
    const float* __restrict__ base = x + (size_t)bc * 3136;

    const float sbn = gbn[c] * rsqrtf(vbn[c] + EPS);
    const float tbn = bbn[c] - mbn[c] * sbn;
    const float w1c = sbn * w1[c];
    const float b1c = b1[c];

    // 8-wide row loader: window col i holds image col 4q-2+i (halo zeroed)
    auto load_row = [&](int row, float* dst) {
        if ((unsigned)row > 55u) {
#pragma unroll
            for (int i = 0; i < 8; ++i) dst[i] = 0.f;
            return;
        }
        const float* rp = base + row * 56;
        float2 Aa = *(const float2*)(rp + (q > 0 ? 4 * q - 2 : 0));   // 8B aligned
        float4 Bv = *(const float4*)(rp + 4 * q);                     // 16B aligned
        float2 Cv = *(const float2*)(rp + (q < 13 ? 4 * q + 4 : 48)); // 16B aligned
        if (q == 0) { Aa.x = 0.f; Aa.y = 0.f; }
        if (q == 13) { Cv.x = 0.f; Cv.y = 0.f; }
        dst[0] = Aa.x; dst[1] = Aa.y;
        dst[2] = Bv.x; dst[3] = Bv.y; dst[4] = Bv.z; dst[5] = Bv.w;
        dst[6] = Cv.x; dst[7] = Cv.y;
    };

    float* op = out + (size_t)bc * 3136 + y0 * 56 + 4 * q;

    if (sel[b]) {
        // ---- 3x3 branch: rolling 3x8 window, 9 taps ----
        const float sk = g3[c] * rsqrtf(v3[c] + EPS);
        const float A = sbn * sk;
        const float Cc = sbn * ((b3[c] - m3[c] * sk) + b1c) + tbn;
        float wg[9];
#pragma unroll
        for (int i = 0; i < 9; ++i) wg[i] = A * w3[c * 9 + i];
        wg[4] += w1c;

        float f[3][8];
        load_row(y0 - 1, f[0]);
        load_row(y0,     f[1]);
#pragma unroll
        for (int j = 0; j < 14; ++j) {
            load_row(y0 + 1 + j, f[(j + 2) % 3]);
            float2 a01 = make_float2(Cc, Cc), a23 = make_float2(Cc, Cc);
#pragma unroll
            for (int ky = 0; ky < 3; ++ky) {
                const float* fr = f[(j + ky) % 3];
#pragma unroll
                for (int kx = 0; kx < 3; ++kx) {
                    const float w = wg[ky * 3 + kx];
                    const float2 w2 = make_float2(w, w);
                    // output col jj needs window col jj+kx+1
                    a01 = pk_fma(w2, make_float2(fr[kx + 1], fr[kx + 2]), a01);
                    a23 = pk_fma(w2, make_float2(fr[kx + 3], fr[kx + 4]), a23);
                }
            }
            *(float4*)op = make_float4(a01.x, a01.y, a23.x, a23.y);
            op += 56;
        }
    } else {
        // ---- 5x5 branch: rolling 5x8 window, 25 taps ----
        const float sk = g5[c] * rsqrtf(v5[c] + EPS);
        const float A = sbn * sk;
        const float Cc = sbn * ((b5[c] - m5[c] * sk) + b1c) + tbn;
        float wg[25];
#pragma unroll
        for (int i = 0; i < 25; ++i) wg[i] = A * w5[c * 25 + i];
        wg[12] += w1c;

        float f[5][8];
#pragma unroll
        for (int i = 0; i < 4; ++i) load_row(y0 - 2 + i, f[i]);
#pragma unroll
        for (int j = 0; j < 14; ++j) {
            load_row(y0 + 2 + j, f[(4 + j) % 5]);
            float2 a01 = make_float2(Cc, Cc), a23 = make_float2(Cc, Cc);
#pragma unroll
            for (int ky = 0; ky < 5; ++ky) {
                const float* fr = f[(j + ky) % 5];
#pragma unroll
                for (int kx = 0; kx < 5; ++kx) {
                    const float w = wg[ky * 5 + kx];
                    const float2 w2 = make_float2(w, w);
                    a01 = pk_fma(w2, make_float2(fr[kx], fr[kx + 1]), a01);
                    a23 = pk_fma(w2, make_float2(fr[kx + 2], fr[kx + 3]), a23);
                }
            }
            *(float4*)op = make_float4(a01.x, a01.y, a23.x, a23.y);
            op += 56;
        }
    }
}

extern "C" void kernel_launch(void* const* d_in, const int* in_sizes, int n_in,
                              void* d_out, int out_size, void* d_ws, size_t ws_size,
                              hipStream_t stream) {
    const float* x   = (const float*)d_in[0];
    const float* w3  = (const float*)d_in[1];
    const float* g3  = (const float*)d_in[2];
    const float* b3  = (const float*)d_in[3];
    const float* m3  = (const float*)d_in[4];
    const float* v3  = (const float*)d_in[5];
    const float* w5  = (const float*)d_in[6];
    const float* g5  = (const float*)d_in[7];
    const float* b5  = (const float*)d_in[8];
    const float* m5  = (const float*)d_in[9];
    const float* v5  = (const float*)d_in[10];
    const float* w1  = (const float*)d_in[11];
    const float* b1  = (const float*)d_in[12];
    const float* gbn = (const float*)d_in[13];
    const float* bbn = (const float*)d_in[14];
    const float* mbn = (const float*)d_in[15];
    const float* vbn = (const float*)d_in[16];
    const float* kw1 = (const float*)d_in[17];
    const float* kg1 = (const float*)d_in[18];
    const float* kb1 = (const float*)d_in[19];
    const float* km1 = (const float*)d_in[20];
    const float* kv1 = (const float*)d_in[21];
    const float* kw2 = (const float*)d_in[22];
    const float* kg2 = (const float*)d_in[23];
    const float* kb2 = (const float*)d_in[24];
    const float* km2 = (const float*)d_in[25];
    const float* kv2 = (const float*)d_in[26];
    float* out = (float*)d_out;

    float* pooled = (float*)d_ws;                          // 6144 floats
    int* sel = (int*)((float*)d_ws + 6144);                // 64 ints

    pool_kernel<<<6144, 256, 0, stream>>>(x, pooled);
    sel_kernel<<<1, 64, 0, stream>>>(pooled, kw1, kg1, kb1, km1, kv1,
                                     kw2, kg2, kb2, km2, kv2, sel);
    conv_kernel<<<1344, 256, 0, stream>>>(
        x, w3, g3, b3, m3, v3, w5, g5, b5, m5, v5, w1, b1,
        gbn, bbn, mbn, vbn, sel, out);
}

// Round 4
// 209.665 us; speedup vs baseline: 2.1907x; 1.0479x over previous
//
#include <hip/hip_runtime.h>
#include <math.h>

#define EPS 1e-5f

typedef float f32x4 __attribute__((ext_vector_type(4)));

// Shapes: B=64, C=96, H=W=56, HW=3136, planes = 6144
// Conv thread map: t = (bc, ysplit 0..3, qstrip 0..13); 56 threads per plane,
// 5376 = 21*256 threads per sample -> every 256-thread block is sample-uniform.

// ---------------- K1: global average pool: x (B,C,56,56) -> pooled (B*C) ----
__global__ __launch_bounds__(256) void pool_kernel(const float* __restrict__ x,
                                                   float* __restrict__ pooled) {
    const int bc = blockIdx.x;
    const float4* xp4 = (const float4*)(x + (size_t)bc * 3136);
    const int tid = threadIdx.x;
    float s = 0.f;
    for (int i = tid; i < 784; i += 256) {
        float4 v = xp4[i];
        s += (v.x + v.y) + (v.z + v.w);
    }
    for (int off = 32; off > 0; off >>= 1) s += __shfl_down(s, off, 64);
    __shared__ float wsum[4];
    if ((tid & 63) == 0) wsum[tid >> 6] = s;
    __syncthreads();
    if (tid == 0) {
        float t = (wsum[0] + wsum[1]) + (wsum[2] + wsum[3]);
        pooled[bc] = t * (1.f / 3136.f);
    }
}

// ---------------- K2: fused predictor-MLP + depthwise conv + BNs ------------
__device__ __forceinline__ float2 pk_fma(float2 a, float2 b, float2 c) {
    return make_float2(fmaf(a.x, b.x, c.x), fmaf(a.y, b.y, c.y));
}

__global__ __launch_bounds__(256) void conv_kernel(
    const float* __restrict__ x, const float* __restrict__ pooled,
    const float* __restrict__ w3, const float* __restrict__ g3,
    const float* __restrict__ b3, const float* __restrict__ m3,
    const float* __restrict__ v3,
    const float* __restrict__ w5, const float* __restrict__ g5,
    const float* __restrict__ b5, const float* __restrict__ m5,
    const float* __restrict__ v5,
    const float* __restrict__ w1, const float* __restrict__ b1,
    const float* __restrict__ gbn, const float* __restrict__ bbn,
    const float* __restrict__ mbn, const float* __restrict__ vbn,
    const float* __restrict__ kw1, const float* __restrict__ kg1,
    const float* __restrict__ kb1, const float* __restrict__ km1,
    const float* __restrict__ kv1,
    const float* __restrict__ kw2, const float* __restrict__ kg2,
    const float* __restrict__ kb2, const float* __restrict__ km2,
    const float* __restrict__ kv2,
    float* __restrict__ out) {
    const int tid = threadIdx.x;
    const int t = blockIdx.x * 256 + tid;   // 344064 total
    const int q = t % 14;
    const int r = t / 14;
    const int ys = r & 3;
    const int bc = r >> 2;
    const int b = bc / 96;                  // block-uniform (21 blocks/sample)
    const int c = bc - b * 96;
    const int y0 = ys * 14;

    // ---- per-block kernel-predictor MLP: sel = (logit0 > logit1) ----
    __shared__ float s_pool[96];
    __shared__ double sh1[4];
    __shared__ int s_sel;
    if (tid < 96) s_pool[tid] = pooled[b * 96 + tid];
    __syncthreads();
    if (tid < 4) {
        const int j = tid;
        double acc = 0.0;
        for (int cc = 0; cc < 96; ++cc)
            acc += (double)s_pool[cc] * (double)kw1[j * 96 + cc];
        double sg = (double)kg1[j] / sqrt((double)kv1[j] + 1e-5);
        double h = acc * sg + ((double)kb1[j] - (double)km1[j] * sg);
        sh1[j] = h * 0.5 * (1.0 + erf(h * 0.70710678118654752440));  // exact gelu
    }
    __syncthreads();
    if (tid == 0) {
        double h2[2];
#pragma unroll
        for (int k = 0; k < 2; ++k) {
            double acc = 0.0;
#pragma unroll
            for (int j = 0; j < 4; ++j) acc += sh1[j] * (double)kw2[k * 4 + j];
            double sg = (double)kg2[k] / sqrt((double)kv2[k] + 1e-5);
            h2[k] = acc * sg + ((double)kb2[k] - (double)km2[k] * sg);
        }
        s_sel = (h2[0] > h2[1]) ? 1 : 0;   // softmax is monotone
    }
    __syncthreads();

    const float* __restrict__ base = x + (size_t)bc * 3136;
    const float sbn = gbn[c] * rsqrtf(vbn[c] + EPS);
    const float tbn = bbn[c] - mbn[c] * sbn;
    const float w1c = sbn * w1[c];
    const float b1c = b1[c];

    // 8-wide row loader: window col i holds image col 4q-2+i (halo zeroed)
    auto load_row = [&](int row, float* dst) {
        if ((unsigned)row > 55u) {
#pragma unroll
            for (int i = 0; i < 8; ++i) dst[i] = 0.f;
            return;
        }
        const float* rp = base + row * 56;
        float2 Aa = *(const float2*)(rp + (q > 0 ? 4 * q - 2 : 0));   // 8B aligned
        float4 Bv = *(const float4*)(rp + 4 * q);                     // 16B aligned
        float2 Cv = *(const float2*)(rp + (q < 13 ? 4 * q + 4 : 48)); // 16B aligned
        if (q == 0) { Aa.x = 0.f; Aa.y = 0.f; }
        if (q == 13) { Cv.x = 0.f; Cv.y = 0.f; }
        dst[0] = Aa.x; dst[1] = Aa.y;
        dst[2] = Bv.x; dst[3] = Bv.y; dst[4] = Bv.z; dst[5] = Bv.w;
        dst[6] = Cv.x; dst[7] = Cv.y;
    };

    float* op = out + (size_t)bc * 3136 + y0 * 56 + 4 * q;

    if (s_sel) {
        // ---- 3x3 branch: rolling 3x8 window, 9 taps ----
        const float sk = g3[c] * rsqrtf(v3[c] + EPS);
        const float A = sbn * sk;
        const float Cc = sbn * ((b3[c] - m3[c] * sk) + b1c) + tbn;
        float wg[9];
#pragma unroll
        for (int i = 0; i < 9; ++i) wg[i] = A * w3[c * 9 + i];
        wg[4] += w1c;

        float f[3][8];
        load_row(y0 - 1, f[0]);
        load_row(y0,     f[1]);
#pragma unroll
        for (int j = 0; j < 14; ++j) {
            load_row(y0 + 1 + j, f[(j + 2) % 3]);
            float2 a01 = make_float2(Cc, Cc), a23 = make_float2(Cc, Cc);
#pragma unroll
            for (int ky = 0; ky < 3; ++ky) {
                const float* fr = f[(j + ky) % 3];
#pragma unroll
                for (int kx = 0; kx < 3; ++kx) {
                    const float w = wg[ky * 3 + kx];
                    const float2 w2 = make_float2(w, w);
                    a01 = pk_fma(w2, make_float2(fr[kx + 1], fr[kx + 2]), a01);
                    a23 = pk_fma(w2, make_float2(fr[kx + 3], fr[kx + 4]), a23);
                }
            }
            f32x4 v; v.x = a01.x; v.y = a01.y; v.z = a23.x; v.w = a23.y;
            __builtin_nontemporal_store(v, (f32x4*)op);
            op += 56;
        }
    } else {
        // ---- 5x5 branch: rolling 5x8 window, 25 taps ----
        const float sk = g5[c] * rsqrtf(v5[c] + EPS);
        const float A = sbn * sk;
        const float Cc = sbn * ((b5[c] - m5[c] * sk) + b1c) + tbn;
        float wg[25];
#pragma unroll
        for (int i = 0; i < 25; ++i) wg[i] = A * w5[c * 25 + i];
        wg[12] += w1c;

        float f[5][8];
#pragma unroll
        for (int i = 0; i < 4; ++i) load_row(y0 - 2 + i, f[i]);
#pragma unroll
        for (int j = 0; j < 14; ++j) {
            load_row(y0 + 2 + j, f[(4 + j) % 5]);
            float2 a01 = make_float2(Cc, Cc), a23 = make_float2(Cc, Cc);
#pragma unroll
            for (int ky = 0; ky < 5; ++ky) {
                const float* fr = f[(j + ky) % 5];
#pragma unroll
                for (int kx = 0; kx < 5; ++kx) {
                    const float w = wg[ky * 5 + kx];
                    const float2 w2 = make_float2(w, w);
                    a01 = pk_fma(w2, make_float2(fr[kx], fr[kx + 1]), a01);
                    a23 = pk_fma(w2, make_float2(fr[kx + 2], fr[kx + 3]), a23);
                }
            }
            f32x4 v; v.x = a01.x; v.y = a01.y; v.z = a23.x; v.w = a23.y;
            __builtin_nontemporal_store(v, (f32x4*)op);
            op += 56;
        }
    }
}

extern "C" void kernel_launch(void* const* d_in, const int* in_sizes, int n_in,
                              void* d_out, int out_size, void* d_ws, size_t ws_size,
                              hipStream_t stream) {
    const float* x   = (const float*)d_in[0];
    const float* w3  = (const float*)d_in[1];
    const float* g3  = (const float*)d_in[2];
    const float* b3  = (const float*)d_in[3];
    const float* m3  = (const float*)d_in[4];
    const float* v3  = (const float*)d_in[5];
    const float* w5  = (const float*)d_in[6];
    const float* g5  = (const float*)d_in[7];
    const float* b5  = (const float*)d_in[8];
    const float* m5  = (const float*)d_in[9];
    const float* v5  = (const float*)d_in[10];
    const float* w1  = (const float*)d_in[11];
    const float* b1  = (const float*)d_in[12];
    const float* gbn = (const float*)d_in[13];
    const float* bbn = (const float*)d_in[14];
    const float* mbn = (const float*)d_in[15];
    const float* vbn = (const float*)d_in[16];
    const float* kw1 = (const float*)d_in[17];
    const float* kg1 = (const float*)d_in[18];
    const float* kb1 = (const float*)d_in[19];
    const float* km1 = (const float*)d_in[20];
    const float* kv1 = (const float*)d_in[21];
    const float* kw2 = (const float*)d_in[22];
    const float* kg2 = (const float*)d_in[23];
    const float* kb2 = (const float*)d_in[24];
    const float* km2 = (const float*)d_in[25];
    const float* kv2 = (const float*)d_in[26];
    float* out = (float*)d_out;

    float* pooled = (float*)d_ws;   // 6144 floats

    pool_kernel<<<6144, 256, 0, stream>>>(x, pooled);
    conv_kernel<<<1344, 256, 0, stream>>>(
        x, pooled, w3, g3, b3, m3, v3, w5, g5, b5, m5, v5, w1, b1,
        gbn, bbn, mbn, vbn,
        kw1, kg1, kb1, km1, kv1, kw2, kg2, kb2, km2, kv2, out);
}